// Round 14
// baseline (196.075 us; speedup 1.0000x reference)
//
#include <hip/hip_runtime.h>

// Shapes fixed by the reference setup:
// B=4096, N=64, OD=128, A=16, H=64, M=32, C=80, agent_divide=N
namespace {
constexpr int Bb = 4096;
constexpr int Nn = 64;
constexpr int OD = 128;

// RA float offsets (time-shared region, 8192 floats = 32 KB) — r12 layout verbatim
constexpr int REL_OFF  = 0;
constexpr int H2_OFF   = 4096;
constexpr int CVV_OFF  = 4096;
constexpr int SVV_OFF  = 5120;
constexpr int PART_OFF = 6144;
}

// 2-row x 4-col GEMM tile: per-output k-sequential fmaf chain — bit-identical
// to r1/r12's accumulation order for each (o, n).
template<int K, bool RELU>
__device__ __forceinline__ void mm64_2(const float* wr0, const float* wr1,
                                       float b0, float b1,
                                       const float* __restrict__ src,
                                       float* __restrict__ dst,
                                       int o0, int n0)
{
  float acc[2][4];
#pragma unroll
  for (int j = 0; j < 4; ++j) { acc[0][j] = b0; acc[1][j] = b1; }
  const float* wr[2] = {wr0, wr1};
#pragma unroll 2
  for (int c = 0; c < K; c += 4) {
    float wv[2][4];
#pragma unroll
    for (int i = 0; i < 2; ++i) {
      float4 t = *(const float4*)(wr[i] + c);
      wv[i][0]=t.x; wv[i][1]=t.y; wv[i][2]=t.z; wv[i][3]=t.w;
    }
#pragma unroll
    for (int k = 0; k < 4; ++k) {
      float4 ov = *(const float4*)(src + (c + k) * Nn + n0);
#pragma unroll
      for (int i = 0; i < 2; ++i) {
        acc[i][0] = fmaf(wv[i][k], ov.x, acc[i][0]);
        acc[i][1] = fmaf(wv[i][k], ov.y, acc[i][1]);
        acc[i][2] = fmaf(wv[i][k], ov.z, acc[i][2]);
        acc[i][3] = fmaf(wv[i][k], ov.w, acc[i][3]);
      }
    }
  }
#pragma unroll
  for (int i = 0; i < 2; ++i) {
    float4 v;
    if (RELU) v = make_float4(fmaxf(acc[i][0],0.f), fmaxf(acc[i][1],0.f),
                              fmaxf(acc[i][2],0.f), fmaxf(acc[i][3],0.f));
    else      v = make_float4(acc[i][0], acc[i][1], acc[i][2], acc[i][3]);
    *(float4*)(dst + (o0 + i) * Nn + n0) = v;
  }
}

// cv1|sv1 K=80 variant: h2 rows 0..63 + act rows 64..79, same k order.
__device__ __forceinline__ void mm80split_2(const float* wr0, const float* wr1,
                                            float b0, float b1,
                                            const float* __restrict__ h2,
                                            const float* __restrict__ act,
                                            float* __restrict__ dst,
                                            int o0, int n0)
{
  float acc[2][4];
#pragma unroll
  for (int j = 0; j < 4; ++j) { acc[0][j] = b0; acc[1][j] = b1; }
  const float* wr[2] = {wr0, wr1};
#pragma unroll 2
  for (int c = 0; c < 80; c += 4) {
    float wv[2][4];
#pragma unroll
    for (int i = 0; i < 2; ++i) {
      float4 t = *(const float4*)(wr[i] + c);
      wv[i][0]=t.x; wv[i][1]=t.y; wv[i][2]=t.z; wv[i][3]=t.w;
    }
#pragma unroll
    for (int k = 0; k < 4; ++k) {
      int ck = c + k;
      const float* rowp = (ck < 64) ? (h2 + ck * Nn) : (act + (ck - 64) * Nn);
      float4 ov = *(const float4*)(rowp + n0);
#pragma unroll
      for (int i = 0; i < 2; ++i) {
        acc[i][0] = fmaf(wv[i][k], ov.x, acc[i][0]);
        acc[i][1] = fmaf(wv[i][k], ov.y, acc[i][1]);
        acc[i][2] = fmaf(wv[i][k], ov.z, acc[i][2]);
        acc[i][3] = fmaf(wv[i][k], ov.w, acc[i][3]);
      }
    }
  }
#pragma unroll
  for (int i = 0; i < 2; ++i) {
    float4 v = make_float4(fmaxf(acc[i][0],0.f), fmaxf(acc[i][1],0.f),
                           fmaxf(acc[i][2],0.f), fmaxf(acc[i][3],0.f));
    *(float4*)(dst + (o0 + i) * Nn + n0) = v;
  }
}

__global__ __launch_bounds__(512, 6)
void critic_fused(const float* __restrict__ obs,
                  const float* __restrict__ actions,
                  const float* __restrict__ relations,
                  const float* __restrict__ enc_w1, const float* __restrict__ enc_b1,
                  const float* __restrict__ enc_w2, const float* __restrict__ enc_b2,
                  const float* __restrict__ cv_w1, const float* __restrict__ cv_b1,
                  const float* __restrict__ cv_w2, const float* __restrict__ cv_b2,
                  const float* __restrict__ sv_w1, const float* __restrict__ sv_b1,
                  const float* __restrict__ sv_w2, const float* __restrict__ sv_b2,
                  const float* __restrict__ pf_w, const float* __restrict__ pf_b,
                  float* __restrict__ out)
{
  // LDS: 32768 (RA) + 16384 (RB) + 4096 (RC) + 256 = 53504 B
  // 8-wave blocks, (512,6) -> 3 blocks/CU = 24 waves/CU (2x r12).
  __shared__ float RA[8192];     // obs -> rel + h2 -> rel + csv + part
  __shared__ float RB[4096];     // h1 [B1,B3) -> X3 [B3,B5)
  __shared__ float RC[1024];     // act [a][n], a 0..15, [B0,B4)
  __shared__ int   amax_s[64];

  const int tid = threadIdx.x;
  const int b = blockIdx.x;

  // ---- TOP: hoist relations into registers (8/thread; pure data movement) ----
  float rvr[8];
#pragma unroll
  for (int i = 0; i < 8; ++i) {
    int idx = tid + i * 512;
    int nn = idx >> 6, k = idx & 63;
    rvr[i] = (k < 63) ? relations[((size_t)nn * Bb + b) * 63 + k] : 1.0f;
  }

  // ---- phase 0: obs -> RA [c][n]; actions -> RC [a][n] (same values as r12) ----
  {
    const float4* src = (const float4*)(obs + (size_t)b * OD * Nn);
    float4* dst = (float4*)RA;
#pragma unroll
    for (int i = 0; i < 4; ++i) dst[tid + i * 512] = src[tid + i * 512];
  }
  for (int idx = tid; idx < Nn * 16; idx += 512) {
    int n = idx >> 4, a = idx & 15;
    RC[a * Nn + n] = actions[((size_t)n * Bb + b) * 16 + a];
  }
  __syncthreads();   // B1: obs, act ready

  const int n0 = (tid & 15) * 4;
  const int o0 = (tid >> 4) * 2;    // 32 row-pairs x 16 col-quads = 512 tiles

  // ---- enc1 (relu): RB(h1) = relu(W1 . obs + b1), K=128 ----
  mm64_2<OD, true>(enc_w1 + (size_t)(o0+0)*OD, enc_w1 + (size_t)(o0+1)*OD,
                   enc_b1[o0], enc_b1[o0+1],
                   RA, RB, o0, n0);
  __syncthreads();   // B2: h1 ready, obs dead -> RA reusable

  // ---- phase 2: rel regs -> RA[REL] (swizzled slots, r12-identical), argmax, enc2 ----
#pragma unroll
  for (int i = 0; i < 8; ++i) {
    int idx = tid + i * 512;
    int nn = idx >> 6, k = idx & 63;
    int j = (k < 63) ? ((k < nn) ? k : k + 1) : nn;   // k==63 -> diagonal (j=nn)
    RA[REL_OFF + nn * 64 + (j ^ (nn & 31))] = rvr[i];
  }
  if (tid < Nn) {
    float best = RC[tid]; int bi = 0;                  // act[0][tid]
#pragma unroll
    for (int a = 1; a < 16; ++a) {
      float v = RC[a * Nn + tid];
      if (v > best) { best = v; bi = a; }   // strict > keeps first (jnp.argmax)
    }
    amax_s[tid] = bi;
  }
  mm64_2<64, false>(enc_w2 + (size_t)(o0+0)*64, enc_w2 + (size_t)(o0+1)*64,
                    enc_b2[o0], enc_b2[o0+1],
                    RB, RA + H2_OFF, o0, n0);
  __syncthreads();   // B3: rel, amax, h2 ready (h1 dead -> RB reusable)

  // ---- cv1|sv1 (relu): RB(X3) = relu([cv_w1;sv_w1] . [h2;act] + b), K=80 ----
  {
    const float* wr[2]; float bb[2];
#pragma unroll
    for (int i = 0; i < 2; ++i) {
      int r = o0 + i;
      if (r < 32) { wr[i] = cv_w1 + (size_t)r * 80;        bb[i] = cv_b1[r]; }
      else        { wr[i] = sv_w1 + (size_t)(r - 32) * 80; bb[i] = sv_b1[r - 32]; }
    }
    mm80split_2(wr[0], wr[1], bb[0], bb[1], RA + H2_OFF, RC, RB, o0, n0);
  }
  __syncthreads();   // B4: X3 ready (h2/act dead)

  // ---- phase 4 (r12 verbatim, tid<256): cv2 & sv2 fp32 -> cvv/svv in RA ----
  if (tid < 256) {
    const int p4n0 = (tid & 31) * 2;
    const int p4o0 = (tid >> 5) * 4;
    const float* wr[4]; float bb[4];
    int srow; float* dst; int dro;
    if (p4o0 < 16) {
      srow = 0; dst = RA + CVV_OFF; dro = p4o0;
#pragma unroll
      for (int i = 0; i < 4; ++i) { wr[i] = cv_w2 + (p4o0 + i) * 32; bb[i] = cv_b2[p4o0 + i]; }
    } else {
      srow = 32; dst = RA + SVV_OFF; dro = p4o0 - 16;
#pragma unroll
      for (int i = 0; i < 4; ++i) { wr[i] = sv_w2 + (p4o0 + i - 16) * 32; bb[i] = sv_b2[p4o0 + i - 16]; }
    }
    float acc[4][2];
#pragma unroll
    for (int i = 0; i < 4; ++i) { acc[i][0] = bb[i]; acc[i][1] = bb[i]; }
#pragma unroll 2
    for (int c = 0; c < 32; c += 4) {
      float wv[4][4];
#pragma unroll
      for (int i = 0; i < 4; ++i) {
        float4 t = *(const float4*)(wr[i] + c);
        wv[i][0]=t.x; wv[i][1]=t.y; wv[i][2]=t.z; wv[i][3]=t.w;
      }
#pragma unroll
      for (int k = 0; k < 4; ++k) {
        float2 ov = *(const float2*)(RB + (srow + c + k) * Nn + p4n0);
#pragma unroll
        for (int i = 0; i < 4; ++i) {
          acc[i][0] = fmaf(wv[i][k], ov.x, acc[i][0]);
          acc[i][1] = fmaf(wv[i][k], ov.y, acc[i][1]);
        }
      }
    }
#pragma unroll
    for (int i = 0; i < 4; ++i)
      *(float2*)(dst + (dro + i) * Nn + p4n0) = make_float2(acc[i][0], acc[i][1]);
  }
  __syncthreads();   // B5: cvv/svv ready

  // ---- phase 5 (r12 verbatim, tid<256): relation mixing + post + gather ----
  if (tid < 256) {
    const int n = tid & 63, cg = tid >> 6;
    const float* cvv = RA + CVV_OFF;
    const float* svv = RA + SVV_OFF;
    const float* relq = RA + REL_OFF + n * 64;
    const int sm = n & 31;
    float acc[4] = {0.f, 0.f, 0.f, 0.f};
#pragma unroll 4
    for (int j = 0; j < 64; j += 4) {
      float r0 = relq[(j    ) ^ sm];
      float r1 = relq[(j + 1) ^ sm];
      float r2 = relq[(j + 2) ^ sm];
      float r3 = relq[(j + 3) ^ sm];
#pragma unroll
      for (int c4 = 0; c4 < 4; ++c4) {
        float4 cv = *(const float4*)(cvv + (cg * 4 + c4) * Nn + j);
        acc[c4] = fmaf(cv.x, r0, acc[c4]);
        acc[c4] = fmaf(cv.y, r1, acc[c4]);
        acc[c4] = fmaf(cv.z, r2, acc[c4]);
        acc[c4] = fmaf(cv.w, r3, acc[c4]);
      }
    }
    int a = amax_s[n];
    const float* pw = pf_w + a * 32;
    float part = 0.f;
#pragma unroll
    for (int c4 = 0; c4 < 4; ++c4) {
      part = fmaf(acc[c4], pw[cg * 4 + c4], part);
      part = fmaf(svv[(cg * 4 + c4) * Nn + n], pw[16 + cg * 4 + c4], part);
    }
    RA[PART_OFF + cg * 64 + n] = part;
  }
  __syncthreads();   // B6

  if (tid < Nn) {
    float q = pf_b[amax_s[tid]]
            + RA[PART_OFF + tid]       + RA[PART_OFF + 64 + tid]
            + RA[PART_OFF + 128 + tid] + RA[PART_OFF + 192 + tid];
    out[(size_t)tid * Bb + b] = q;   // q[n, b, 0]
  }
}

extern "C" void kernel_launch(void* const* d_in, const int* in_sizes, int n_in,
                              void* d_out, int out_size, void* d_ws, size_t ws_size,
                              hipStream_t stream) {
  const float* obs       = (const float*)d_in[0];
  const float* actions   = (const float*)d_in[1];
  const float* relations = (const float*)d_in[2];
  const float* enc_w1    = (const float*)d_in[3];
  const float* enc_b1    = (const float*)d_in[4];
  const float* enc_w2    = (const float*)d_in[5];
  const float* enc_b2    = (const float*)d_in[6];
  const float* cv_w1     = (const float*)d_in[7];
  const float* cv_b1     = (const float*)d_in[8];
  const float* cv_w2     = (const float*)d_in[9];
  const float* cv_b2     = (const float*)d_in[10];
  const float* sv_w1     = (const float*)d_in[11];
  const float* sv_b1     = (const float*)d_in[12];
  const float* sv_w2     = (const float*)d_in[13];
  const float* sv_b2     = (const float*)d_in[14];
  const float* pf_w      = (const float*)d_in[15];
  const float* pf_b      = (const float*)d_in[16];

  critic_fused<<<dim3(Bb), dim3(512), 0, stream>>>(
      obs, actions, relations,
      enc_w1, enc_b1, enc_w2, enc_b2,
      cv_w1, cv_b1, cv_w2, cv_b2,
      sv_w1, sv_b1, sv_w2, sv_b2,
      pf_w, pf_b, (float*)d_out);
}

// Round 15
// 132.437 us; speedup vs baseline: 1.4805x; 1.4805x over previous
//
#include <hip/hip_runtime.h>

// Shapes fixed by the reference setup:
// B=4096, N=64, OD=128, A=16, H=64, M=32, C=80 (pad 96), agent_divide=N
namespace {
constexpr int Bb = 4096;
constexpr int Nn = 64;
constexpr int OD = 128;

// d_ws layout (f16 units): pre-split weight fragment tables, frag-major lane-major.
// frag payload = 64 lanes x 8 f16 = 512 f16.
constexpr int E1H = 0;       // enc1 hi: 16 frags (w*4+kk)
constexpr int E1L = 8192;    // enc1 lo'
constexpr int E2H = 16384;   // enc2 hi: 8 frags (w*2+kk)
constexpr int E2L = 20480;
constexpr int C1H = 24576;   // cv1|sv1 hi: 12 frags (w*3+kk), zeros for k>=80
constexpr int C1L = 30720;
}

typedef __attribute__((ext_vector_type(8))) _Float16 f16x8;
typedef __attribute__((ext_vector_type(4))) _Float16 f16x4;
typedef __attribute__((ext_vector_type(4))) float    f32x4;

// XOR-swizzled byte offset in [n][K] f16 plane (rowb bytes/row).
__device__ __forceinline__ int swz(int n, int rowb, int k) {
  return n * rowb + ((2 * k) ^ ((n & 7) << 4));
}
__device__ __forceinline__ int swz4(int n, int rowb, int k) {
  return n * rowb + ((2 * k) ^ ((n & 3) << 4));
}

// ---------------- prep kernel: split weights into f16 hi / scaled-lo tables ----------------
__global__ __launch_bounds__(256)
void prep_weights(const float* __restrict__ ew1, const float* __restrict__ ew2,
                  const float* __restrict__ cw1, const float* __restrict__ sw1,
                  _Float16* __restrict__ ws) {
  int idx = blockIdx.x * 256 + threadIdx.x;   // index in hi-table space (18432 elems)
  if (idx >= 18432) return;
  int pos, hbase, lbase;
  float v;
  if (idx < 8192) {                 // enc1: frag = w*4+kk, k in 0..127
    pos = idx; hbase = E1H; lbase = E1L;
    int frag = pos >> 9, r = pos & 511, lane = r >> 3, i = r & 7;
    int w = frag >> 2, kk = frag & 3;
    int row = w * 16 + (lane & 15), k = kk * 32 + (lane >> 4) * 8 + i;
    v = ew1[row * 128 + k];
  } else if (idx < 12288) {         // enc2: frag = w*2+kk, k in 0..63
    pos = idx - 8192; hbase = E2H; lbase = E2L;
    int frag = pos >> 9, r = pos & 511, lane = r >> 3, i = r & 7;
    int w = frag >> 1, kk = frag & 1;
    int row = w * 16 + (lane & 15), k = kk * 32 + (lane >> 4) * 8 + i;
    v = ew2[row * 64 + k];
  } else {                          // cv1|sv1: frag = w*3+kk, k in 0..95 (>=80 zero)
    pos = idx - 12288; hbase = C1H; lbase = C1L;
    int frag = pos >> 9, r = pos & 511, lane = r >> 3, i = r & 7;
    int w = frag / 3, kk = frag % 3;
    int row = w * 16 + (lane & 15), k = kk * 32 + (lane >> 4) * 8 + i;
    v = 0.f;
    if (k < 80) v = (row < 32) ? cw1[row * 80 + k] : sw1[(row - 32) * 80 + k];
  }
  _Float16 h = (_Float16)v;
  ws[hbase + pos] = h;
  ws[lbase + pos] = (_Float16)((v - (float)h) * 1024.f);  // scaled Dekker lo (FTZ-safe)
}

// ---------------- main fused kernel ----------------
__global__ __launch_bounds__(256, 2)
void critic_fused(const float* __restrict__ obs,
                  const float* __restrict__ actions,
                  const float* __restrict__ relations,
                  const float* __restrict__ enc_b1, const float* __restrict__ enc_b2,
                  const float* __restrict__ cv_b1,  const float* __restrict__ sv_b1,
                  const float* __restrict__ cv_w2, const float* __restrict__ cv_b2,
                  const float* __restrict__ sv_w2, const float* __restrict__ sv_b2,
                  const float* __restrict__ pf_w, const float* __restrict__ pf_b,
                  const _Float16* __restrict__ ws,
                  float* __restrict__ out)
{
  // LDS: 16640 + 32768 + 16384 + 8192 + 256 = 74240 B -> 2 blocks/CU
  __shared__ float rel_s[64 * 65];                 // rel[n][65], read in phase 5
  __shared__ __align__(16) char RA[32768];         // X0h(0)/X0l(16K) -> sah(0)/sal(8K) + X3 f32(16K)
  __shared__ __align__(16) char RB[16384];         // X1h(0)/X1l(8K)  -> cvv/svv/part f32
  __shared__ __align__(16) char RC[8192];          // acth(0)/actl(4K), alive to B4
  __shared__ int amax_s[64];

  char* X0h = RA;                       // rowb 256 (128 k)
  char* X0l = RA + 16384;
  char* sah = RA;                       // rowb 128 (64 k), post-B2
  char* sal = RA + 8192;
  float* X3 = (float*)(RA + 16384);     // fp32 [o][n] = [64][64], post-B3
  char* X1h = RB;                       // rowb 128
  char* X1l = RB + 8192;
  float* csv  = (float*)RB;             // post-B3: cvv[16][64] @0, svv @1024, part[4][64] @2048
  char* acth = RC;                      // rowb 64 (32 k': act | zeros)
  char* actl = RC + 4096;

  const int tid = threadIdx.x;
  const int b = blockIdx.x;
  const int lane = tid & 63;
  const int w = tid >> 6;               // wave id 0..3
  const int lo16 = lane & 15;
  const int hig  = lane >> 4;
  const int o0 = w * 16;                // this wave's 16 output rows
  const f16x8* wsv = (const f16x8*)ws;  // f16x8 granules; table base/8

  // ---- phase 0: stage obs (transpose+split) and actions (split) ----
  {
    int n = tid & 63, chunk = tid >> 6;
    const float* p = obs + (size_t)b * (OD * Nn) + (size_t)chunk * 32 * Nn + n;
#pragma unroll
    for (int g = 0; g < 4; ++g) {
      f16x8 uh, ul;
#pragma unroll
      for (int j = 0; j < 8; ++j) {
        float v = p[(g * 8 + j) * Nn];       // coalesced across lanes
        _Float16 h = (_Float16)v;
        uh[j] = h;
        ul[j] = (_Float16)((v - (float)h) * 1024.f);
      }
      int off = swz(n, 256, chunk * 32 + g * 8);
      *(f16x8*)(X0h + off) = uh;
      *(f16x8*)(X0l + off) = ul;
    }
  }
  {
    int n = tid >> 2, a0 = (tid & 3) * 4;
    float4 v4 = *(const float4*)(actions + ((size_t)n * Bb + b) * 16 + a0);
    float vv[4] = {v4.x, v4.y, v4.z, v4.w};
    f16x4 uh, ul;
#pragma unroll
    for (int r = 0; r < 4; ++r) {
      _Float16 h = (_Float16)vv[r];
      uh[r] = h;
      ul[r] = (_Float16)((vv[r] - (float)h) * 1024.f);
    }
    int offa = swz4(n, 64, a0);
    *(f16x4*)(acth + offa) = uh;
    *(f16x4*)(actl + offa) = ul;
    f16x4 z = {};
    int offz = swz4(n, 64, 16 + a0);
    *(f16x4*)(acth + offz) = z;
    *(f16x4*)(actl + offz) = z;
  }
  __syncthreads();   // B1: X0, act ready

  // ---- enc1 (relu): X1 = relu(W1 . X0 + b1), K=128, split-MFMA (A in regs) ----
  {
    f32x4 hac[4] = {}, lac[4] = {};
#pragma unroll
    for (int kk = 0; kk < 4; ++kk) {
      int frag = w * 4 + kk;
      f16x8 ah = wsv[(E1H >> 3) + frag * 64 + lane];
      f16x8 al = wsv[(E1L >> 3) + frag * 64 + lane];
      int k0 = kk * 32 + hig * 8;
#pragma unroll
      for (int t = 0; t < 4; ++t) {
        int off = swz(t * 16 + lo16, 256, k0);
        f16x8 bh = *(const f16x8*)(X0h + off);
        f16x8 bl = *(const f16x8*)(X0l + off);
        hac[t] = __builtin_amdgcn_mfma_f32_16x16x32_f16(ah, bh, hac[t], 0, 0, 0);
        lac[t] = __builtin_amdgcn_mfma_f32_16x16x32_f16(ah, bl, lac[t], 0, 0, 0);
        lac[t] = __builtin_amdgcn_mfma_f32_16x16x32_f16(al, bh, lac[t], 0, 0, 0);
      }
    }
#pragma unroll
    for (int t = 0; t < 4; ++t) {
      f16x4 ph, pl;
#pragma unroll
      for (int r = 0; r < 4; ++r) {
        float v = hac[t][r] + lac[t][r] * (1.f / 1024.f) + enc_b1[o0 + hig * 4 + r];
        v = fmaxf(v, 0.f);
        _Float16 h = (_Float16)v;
        ph[r] = h;
        pl[r] = (_Float16)((v - (float)h) * 1024.f);
      }
      int off = swz(t * 16 + lo16, 128, o0 + hig * 4);
      *(f16x4*)(X1h + off) = ph;
      *(f16x4*)(X1l + off) = pl;
    }
  }
  __syncthreads();   // B2: X1 ready (X0 dead -> RA reusable)

  // ---- phase 2: rel -> rel_s, argmax (exact fp32 global), enc2 -> sa planes ----
  for (int idx = tid; idx < 4096; idx += 256) {
    int n = idx >> 6, k = idx & 63;
    if (k < 63) {
      float v = relations[((size_t)n * Bb + b) * 63 + k];
      int j = (k < n) ? k : k + 1;       // j != n
      rel_s[n * 65 + j] = v;
    } else {
      rel_s[n * 65 + n] = 1.0f;          // diagonal
    }
  }
  if (tid < Nn) {
    const float* ar = actions + ((size_t)tid * Bb + b) * 16;
    float best = ar[0]; int bi = 0;
#pragma unroll
    for (int a = 1; a < 16; ++a) {
      float v = ar[a];
      if (v > best) { best = v; bi = a; }   // strict > keeps first (jnp.argmax)
    }
    amax_s[tid] = bi;
  }
  {
    f32x4 hac[4] = {}, lac[4] = {};
#pragma unroll
    for (int kk = 0; kk < 2; ++kk) {
      int frag = w * 2 + kk;
      f16x8 ah = wsv[(E2H >> 3) + frag * 64 + lane];
      f16x8 al = wsv[(E2L >> 3) + frag * 64 + lane];
      int k0 = kk * 32 + hig * 8;
#pragma unroll
      for (int t = 0; t < 4; ++t) {
        int off = swz(t * 16 + lo16, 128, k0);
        f16x8 bh = *(const f16x8*)(X1h + off);
        f16x8 bl = *(const f16x8*)(X1l + off);
        hac[t] = __builtin_amdgcn_mfma_f32_16x16x32_f16(ah, bh, hac[t], 0, 0, 0);
        lac[t] = __builtin_amdgcn_mfma_f32_16x16x32_f16(ah, bl, lac[t], 0, 0, 0);
        lac[t] = __builtin_amdgcn_mfma_f32_16x16x32_f16(al, bh, lac[t], 0, 0, 0);
      }
    }
#pragma unroll
    for (int t = 0; t < 4; ++t) {
      f16x4 ph, pl;
#pragma unroll
      for (int r = 0; r < 4; ++r) {
        float v = hac[t][r] + lac[t][r] * (1.f / 1024.f) + enc_b2[o0 + hig * 4 + r];   // no relu
        _Float16 h = (_Float16)v;
        ph[r] = h;
        pl[r] = (_Float16)((v - (float)h) * 1024.f);
      }
      int off = swz(t * 16 + lo16, 128, o0 + hig * 4);
      *(f16x4*)(sah + off) = ph;
      *(f16x4*)(sal + off) = pl;
    }
  }
  __syncthreads();   // B3: sa ready (X1 dead -> RB reusable)

  // ---- cv1|sv1 (relu): X3 = relu([cv_w1;sv_w1].[h2;act;0] + b), K=96, fp32 out ----
  {
    f32x4 hac[4] = {}, lac[4] = {};
#pragma unroll
    for (int kk = 0; kk < 3; ++kk) {
      int frag = w * 3 + kk;
      f16x8 ah = wsv[(C1H >> 3) + frag * 64 + lane];
      f16x8 al = wsv[(C1L >> 3) + frag * 64 + lane];
#pragma unroll
      for (int t = 0; t < 4; ++t) {
        int n = t * 16 + lo16;
        f16x8 bh, bl;
        if (kk < 2) {
          int off = swz(n, 128, kk * 32 + hig * 8);
          bh = *(const f16x8*)(sah + off);
          bl = *(const f16x8*)(sal + off);
        } else {
          int off = swz4(n, 64, hig * 8);          // act | zeros
          bh = *(const f16x8*)(acth + off);
          bl = *(const f16x8*)(actl + off);
        }
        hac[t] = __builtin_amdgcn_mfma_f32_16x16x32_f16(ah, bh, hac[t], 0, 0, 0);
        lac[t] = __builtin_amdgcn_mfma_f32_16x16x32_f16(ah, bl, lac[t], 0, 0, 0);
        lac[t] = __builtin_amdgcn_mfma_f32_16x16x32_f16(al, bh, lac[t], 0, 0, 0);
      }
    }
#pragma unroll
    for (int t = 0; t < 4; ++t)
#pragma unroll
      for (int r = 0; r < 4; ++r) {
        int o = o0 + hig * 4 + r;
        float bb = (o < 32) ? cv_b1[o] : sv_b1[o - 32];
        float v = hac[t][r] + lac[t][r] * (1.f / 1024.f) + bb;
        X3[o * Nn + t * 16 + lo16] = fmaxf(v, 0.f);   // fp32, r1 [o][n] layout
      }
  }
  __syncthreads();   // B4: X3 ready (sa/act dead)

  // ---- phase 4: cv2 & sv2 fp32 -> cvv/svv (weights L1-hot) ----
  {
    const int p4n0 = (tid & 31) * 2;
    const int p4o0 = (tid >> 5) * 4;
    const float* wr[4]; float bb[4];
    int srow; float* dst; int dro;
    if (p4o0 < 16) {
      srow = 0; dst = csv; dro = p4o0;
#pragma unroll
      for (int i = 0; i < 4; ++i) { wr[i] = cv_w2 + (p4o0 + i) * 32; bb[i] = cv_b2[p4o0 + i]; }
    } else {
      srow = 32; dst = csv + 1024; dro = p4o0 - 16;
#pragma unroll
      for (int i = 0; i < 4; ++i) { wr[i] = sv_w2 + (p4o0 + i - 16) * 32; bb[i] = sv_b2[p4o0 + i - 16]; }
    }
    float acc[4][2];
#pragma unroll
    for (int i = 0; i < 4; ++i) { acc[i][0] = bb[i]; acc[i][1] = bb[i]; }
#pragma unroll 2
    for (int c = 0; c < 32; c += 4) {
      float wv[4][4];
#pragma unroll
      for (int i = 0; i < 4; ++i) {
        float4 t = *(const float4*)(wr[i] + c);
        wv[i][0]=t.x; wv[i][1]=t.y; wv[i][2]=t.z; wv[i][3]=t.w;
      }
#pragma unroll
      for (int k = 0; k < 4; ++k) {
        float2 ov = *(const float2*)(X3 + (srow + c + k) * Nn + p4n0);
#pragma unroll
        for (int i = 0; i < 4; ++i) {
          acc[i][0] = fmaf(wv[i][k], ov.x, acc[i][0]);
          acc[i][1] = fmaf(wv[i][k], ov.y, acc[i][1]);
        }
      }
    }
#pragma unroll
    for (int i = 0; i < 4; ++i)
      *(float2*)(dst + (dro + i) * Nn + p4n0) = make_float2(acc[i][0], acc[i][1]);
  }
  __syncthreads();   // B5: cvv/svv ready

  // ---- phase 5: relation mixing + post + argmax gather (fp32) ----
  {
    const int n = tid & 63, cg = tid >> 6;
    const float* cvv = csv;
    const float* svv = csv + 1024;
    const float* relr = rel_s + n * 65;
    float acc[4] = {0.f, 0.f, 0.f, 0.f};
#pragma unroll 4
    for (int j = 0; j < 64; j += 4) {
      float r0 = relr[j], r1 = relr[j+1], r2 = relr[j+2], r3 = relr[j+3];
#pragma unroll
      for (int c4 = 0; c4 < 4; ++c4) {
        float4 cv = *(const float4*)(cvv + (cg * 4 + c4) * Nn + j);
        acc[c4] = fmaf(cv.x, r0, acc[c4]);
        acc[c4] = fmaf(cv.y, r1, acc[c4]);
        acc[c4] = fmaf(cv.z, r2, acc[c4]);
        acc[c4] = fmaf(cv.w, r3, acc[c4]);
      }
    }
    int a = amax_s[n];
    const float* pw = pf_w + a * 32;
    float part = 0.f;
#pragma unroll
    for (int c4 = 0; c4 < 4; ++c4) {
      part = fmaf(acc[c4], pw[cg * 4 + c4], part);
      part = fmaf(svv[(cg * 4 + c4) * Nn + n], pw[16 + cg * 4 + c4], part);
    }
    csv[2048 + cg * 64 + n] = part;
  }
  __syncthreads();   // B6

  if (tid < Nn) {
    float q = pf_b[amax_s[tid]]
            + csv[2048 + tid]       + csv[2048 + 64 + tid]
            + csv[2048 + 128 + tid] + csv[2048 + 192 + tid];
    out[(size_t)tid * Bb + b] = q;   // q[n, b, 0]
  }
}

extern "C" void kernel_launch(void* const* d_in, const int* in_sizes, int n_in,
                              void* d_out, int out_size, void* d_ws, size_t ws_size,
                              hipStream_t stream) {
  const float* obs       = (const float*)d_in[0];
  const float* actions   = (const float*)d_in[1];
  const float* relations = (const float*)d_in[2];
  const float* enc_w1    = (const float*)d_in[3];
  const float* enc_b1    = (const float*)d_in[4];
  const float* enc_w2    = (const float*)d_in[5];
  const float* enc_b2    = (const float*)d_in[6];
  const float* cv_w1     = (const float*)d_in[7];
  const float* cv_b1     = (const float*)d_in[8];
  const float* cv_w2     = (const float*)d_in[9];
  const float* cv_b2     = (const float*)d_in[10];
  const float* sv_w1     = (const float*)d_in[11];
  const float* sv_b1     = (const float*)d_in[12];
  const float* sv_w2     = (const float*)d_in[13];
  const float* sv_b2     = (const float*)d_in[14];
  const float* pf_w      = (const float*)d_in[15];
  const float* pf_b      = (const float*)d_in[16];

  _Float16* ws = (_Float16*)d_ws;   // needs 73728 B

  prep_weights<<<dim3((18432 + 255) / 256), dim3(256), 0, stream>>>(
      enc_w1, enc_w2, cv_w1, sv_w1, ws);

  critic_fused<<<dim3(Bb), dim3(256), 0, stream>>>(
      obs, actions, relations,
      enc_b1, enc_b2, cv_b1, sv_b1,
      cv_w2, cv_b2, sv_w2, sv_b2,
      pf_w, pf_b, ws, (float*)d_out);
}